// Round 10
// baseline (181.744 us; speedup 1.0000x reference)
//
#include <hip/hip_runtime.h>
#include <math.h>

// Capsule dynamic routing, B=64, R=4608, C=32, Din=Dout=16, 3 iters.
// b-logits are linear in v -> keep only vsum; u_hat recomputed per pass via
// mfma_f32_32x32x16_f16 (K=16==Din, A=Wfrag, B=xfrag -> D[(c,o)][b]).
//
// Round-10: delete the wp intermediate entirely (its producer was pinned at
// ~85us across 3 implementations with every pipe idle). Each pass stages
// W[r] f32 straight to LDS (coalesced global_load_lds, double-buffered,
// counted vmcnt(2)) and builds its f16 A-fragment with 8 strided LDS reads
// (bit10->bit6 XOR swizzle, numerically validated in round 9, 2-way = free).
// Removes 75.5MB wp writes + 226MB wp reads; passes 2-3 re-read W from L3.

#define B_    64
#define R_    4608
#define C_    32
#define RB    36
#define NBLK  (R_ / RB)      // 128
#define SELEM 32768          // 512 * 64

typedef _Float16 half8  __attribute__((ext_vector_type(8)));
typedef _Float16 half2v __attribute__((ext_vector_type(2)));
typedef float    f32x16 __attribute__((ext_vector_type(16)));

__device__ __forceinline__ void gload_lds16(const void* g, void* l) {
    __builtin_amdgcn_global_load_lds(
        (const __attribute__((address_space(1))) void*)g,
        (__attribute__((address_space(3))) void*)l, 16, 0, 0);
}

// ------------------------------------------------------------------ x prep
// x [64][4608][16] f32  ->  xa [4608][64][16] f16   (576 blocks x 512)
__global__ __launch_bounds__(512)
void caps_xconv(const float* __restrict__ x, _Float16* __restrict__ xa)
{
    const int idx = blockIdx.x * 512 + threadIdx.x;   // r*64 + b
    const int r = idx >> 6, b = idx & 63;
    const float4* xs = (const float4*)(x + ((size_t)b * R_ + r) * 16);
    const float4 A = xs[0], Bv = xs[1], Cv = xs[2], Dv = xs[3];
    half8 lo, hi;
    lo[0]=(_Float16)A.x;  lo[1]=(_Float16)A.y;  lo[2]=(_Float16)A.z;  lo[3]=(_Float16)A.w;
    lo[4]=(_Float16)Bv.x; lo[5]=(_Float16)Bv.y; lo[6]=(_Float16)Bv.z; lo[7]=(_Float16)Bv.w;
    hi[0]=(_Float16)Cv.x; hi[1]=(_Float16)Cv.y; hi[2]=(_Float16)Cv.z; hi[3]=(_Float16)Cv.w;
    hi[4]=(_Float16)Dv.x; hi[5]=(_Float16)Dv.y; hi[6]=(_Float16)Dv.z; hi[7]=(_Float16)Dv.w;
    half8* dst = (half8*)(xa + ((size_t)idx << 4));
    dst[0] = lo; dst[1] = hi;
}

// ------------------------------------------------------------- MFMA pass
// D = mfma(A=Wfrag, B=xfrag): D[row=(c,o)][col=b_loc].
// lane: col b_loc = lane&31; rows (regs): R(e,h) = (e&3)+8*(e>>2)+4*h.
// wave wv owns N-tile wv: c = 2*wv + (l31>>4), o = l31&15, k = 8h+e.
// W[r] staged f32 in LDS, swizzled LDS[D]=W[D^((D>>10&1)<<6)] (bit6 flip by
// c-LSB); A-frag built by 8 strided reads at (c*1024+h*512+o*4+e*64)^key.
template<bool FIRST>
__global__ __launch_bounds__(1024, 4)
void caps_mfma(const _Float16* __restrict__ xa, const float* __restrict__ Wg,
               const float* __restrict__ vsumT, float* __restrict__ sdst)
{
    __shared__ float wl[2][8192];             // 64 KB W double buffer
    __shared__ _Float16 xalds[RB * 512];      // 36 KB
    __shared__ float t_lds[32][33];
    __shared__ float c_lds[32][33];

    const int tid  = threadIdx.x;
    const int lane = tid & 63;
    const int wv   = tid >> 6;                // 0..15 = N-tile
    const int h    = lane >> 5;
    const int l31  = lane & 31;
    const int bh   = blockIdx.y;              // b-half
    const int r0   = blockIdx.x * RB;
    const int bg   = bh * 32 + l31;           // global b owned by this lane

    // ---- stage x tile (coalesced; involution swizzle validated round 6) ----
    {
        const int slx = (lane << 4) ^ (((lane >> 3) & 7) << 4);
        for (int t = wv; t < RB; t += 16) {
            const char* src = (const char*)xa + (size_t)(r0 + t) * 2048 + bh * 1024 + slx;
            gload_lds16(src, (char*)xalds + t * 1024);
        }
    }

    // ---- W stage macro: 32 KB per r, pre-swizzled source (round-9 validated)
#define WSTAGE(buf, r)                                                          \
    do {                                                                        \
        const char* wsrc_ = (const char*)Wg + ((size_t)(r) << 15);              \
        _Pragma("unroll")                                                       \
        for (int j_ = 0; j_ < 2; ++j_) {                                        \
            const int D_ = (j_ << 14) + (tid << 4);                             \
            const int S_ = D_ ^ (((D_ >> 10) & 1) << 6);                        \
            gload_lds16(wsrc_ + S_, (char*)wl[buf] + D_);                       \
        }                                                                       \
    } while (0)

    WSTAGE(0, r0);

    f32x16 sacc, zf;
#pragma unroll
    for (int k = 0; k < 16; ++k) { sacc[k] = 0.f; zf[k] = 0.f; }

    // v[b][c][o] per lane, f16-packed (8 VGPRs)
    half2v vh[8];
    if (!FIRST) {
#pragma unroll
        for (int e = 0; e < 16; ++e) {
            const int g = wv * 32 + (e & 3) + 8 * (e >> 2) + 4 * h;
            vh[e >> 1][e & 1] = (_Float16)vsumT[(size_t)g * 64 + bg];
        }
    }

    asm volatile("s_waitcnt vmcnt(0)" ::: "memory");
    __syncthreads();

    const int avoff = ((l31 << 5) + (h << 4)) ^ (((l31 >> 2) & 7) << 4);
    const int c_    = 2 * wv + (l31 >> 4);
    const int wbase = c_ * 1024 + h * 512 + (l31 & 15) * 4;   // linear byte addr
    const int wkey  = (c_ & 1) << 6;                          // swizzle key

#pragma unroll 1
    for (int t = 0; t < RB; ++t) {
        const int cur = t & 1;

        if (FIRST) __builtin_amdgcn_s_barrier();  // prev frag-readers done
        if (t + 1 < RB) {
            WSTAGE(cur ^ 1, r0 + t + 1);
            asm volatile("s_waitcnt vmcnt(2)" ::: "memory");
        } else {
            asm volatile("s_waitcnt vmcnt(0)" ::: "memory");
        }
        __builtin_amdgcn_s_barrier();             // tile t landed for everyone

        // ---- build f16 A-frag from staged f32 W (8 reads, 2-way = free) ----
        const char* lb = (const char*)wl[cur];
        half8 bc;
#pragma unroll
        for (int e = 0; e < 8; ++e)
            bc[e] = (_Float16)*(const float*)(lb + ((wbase + (e << 6)) ^ wkey));

        const half8 av = *(const half8*)((const char*)xalds + t * 1024 + avoff);

        f32x16 u;
        if (FIRST) {
            sacc = __builtin_amdgcn_mfma_f32_32x32x16_f16(bc, av, sacc, 0, 0, 0);
            continue;
        }
        u = __builtin_amdgcn_mfma_f32_32x32x16_f16(bc, av, zf, 0, 0, 0);

        // ---- logits: in-register o-reduce + one half-swap fold per capsule
        {
            float s0 = 0.f, s1 = 0.f;
#pragma unroll
            for (int e2 = 0; e2 < 4; ++e2) {
                s0 += u[2 * e2]         * (float)vh[e2][0];
                s0 += u[2 * e2 + 1]     * (float)vh[e2][1];
                s1 += u[8 + 2 * e2]     * (float)vh[4 + e2][0];
                s1 += u[8 + 2 * e2 + 1] * (float)vh[4 + e2][1];
            }
            s0 += __shfl_xor(s0, 32);
            s1 += __shfl_xor(s1, 32);
            if (h == 0) {
                t_lds[2 * wv    ][l31] = s0;
                t_lds[2 * wv + 1][l31] = s1;
            }
        }
        __syncthreads();

        // ---- softmax over c: threads 0..511 -> (c-pair a_, local b2) ----
        if (tid < 512) {
            const int a_ = lane & 15;
            const int b2 = tid >> 4;          // 0..31
            const float tA = t_lds[2 * a_][b2];
            const float tB = t_lds[2 * a_ + 1][b2];
            float m = fmaxf(tA, tB);
            m = fmaxf(m, __shfl_xor(m, 1));
            m = fmaxf(m, __shfl_xor(m, 2));
            m = fmaxf(m, __shfl_xor(m, 4));
            m = fmaxf(m, __shfl_xor(m, 8));
            const float eA = __expf(tA - m);
            const float eB = __expf(tB - m);
            float zs = eA + eB;
            zs += __shfl_xor(zs, 1);
            zs += __shfl_xor(zs, 2);
            zs += __shfl_xor(zs, 4);
            zs += __shfl_xor(zs, 8);
            const float inv = 1.0f / zs;
            c_lds[2 * a_][b2]     = eA * inv;
            c_lds[2 * a_ + 1][b2] = eB * inv;
        }
        __syncthreads();

        // ---- accumulate: sacc += c_ij * u (2 broadcast b32 reads) ----
        {
            const float c0v = c_lds[2 * wv    ][l31];
            const float c1v = c_lds[2 * wv + 1][l31];
#pragma unroll
            for (int e = 0; e < 8; ++e)  sacc[e] += c0v * u[e];
#pragma unroll
            for (int e = 8; e < 16; ++e) sacc[e] += c1v * u[e];
        }
    }
#undef WSTAGE

    // ---- epilogue: transposed partial store sT[g][b] (coalesced over b) ----
    const float scale = FIRST ? 0.03125f : 1.0f;
    float* sp = sdst + ((size_t)blockIdx.x << 15);
#pragma unroll
    for (int e = 0; e < 16; ++e) {
        const int g = wv * 32 + (e & 3) + 8 * (e >> 2) + 4 * h;
        sp[(size_t)g * 64 + bg] = sacc[e] * scale;
    }
}

// ------------------------------------------------- reductions + squash
// stage 1: 128 partials -> 8 (elementwise)
__global__ __launch_bounds__(256)
void caps_reduce1(const float* __restrict__ sp, float* __restrict__ s2)
{
    const int e  = blockIdx.x * 256 + threadIdx.x;
    const int pg = blockIdx.y;
    const float* p0 = sp + (size_t)pg * 16 * SELEM + e;
    float a = 0.0f;
#pragma unroll 8
    for (int p = 0; p < 16; ++p) a += p0[(size_t)p * SELEM];
    s2[pg * SELEM + e] = a;
}

// stage 2 on transposed layout: thread owns (c,b), o in registers -> no shfl.
// mode 0: vsumT = v; 1: vsumT += v; 2: out[b][c][o] = v.
__global__ __launch_bounds__(64)
void caps_reduce2T(const float* __restrict__ src, float* __restrict__ vsumT,
                   float* __restrict__ out, int mode)
{
    const int c = blockIdx.x;                 // 0..31
    const int b = threadIdx.x;                // 0..63
    float a[16];
#pragma unroll
    for (int o = 0; o < 16; ++o) a[o] = 0.0f;
    for (int p = 0; p < 8; ++p)
#pragma unroll
        for (int o = 0; o < 16; ++o)
            a[o] += src[(size_t)p * SELEM + c * 1024 + o * 64 + b];
    float sq = 0.0f;
#pragma unroll
    for (int o = 0; o < 16; ++o) sq += a[o] * a[o];
    const float n  = sqrtf(sq);
    const float sc = sq / (1.0f + sq) / (n + 1e-8f);
    if (mode == 2) {
#pragma unroll
        for (int o = 0; o < 16; ++o)
            out[(size_t)b * 512 + c * 16 + o] = a[o] * sc;
    } else if (mode == 0) {
#pragma unroll
        for (int o = 0; o < 16; ++o)
            vsumT[c * 1024 + o * 64 + b] = a[o] * sc;
    } else {
#pragma unroll
        for (int o = 0; o < 16; ++o)
            vsumT[c * 1024 + o * 64 + b] += a[o] * sc;
    }
}

// old-layout reduce2 (tier-3 fallback only)
__global__ __launch_bounds__(256)
void caps_reduce2(const float* __restrict__ src, int P,
                  float* __restrict__ vsum, float* __restrict__ out, int mode)
{
    const int e = blockIdx.x * 256 + threadIdx.x;
    float a = 0.0f;
    for (int p = 0; p < P; ++p) a += src[(size_t)p * SELEM + e];
    float sq = a * a;
#pragma unroll
    for (int off = 8; off >= 1; off >>= 1) sq += __shfl_xor(sq, off);
    const float n = sqrtf(sq);
    const float v = a * (sq / (1.0f + sq) / (n + 1e-8f));
    if (mode == 0)      vsum[e] = v;
    else if (mode == 1) vsum[e] += v;
    else                out[e] = v;
}

// ------------------------------------- tier-3 fallback: fp32 VALU path
template<bool FIRST>
__global__ __launch_bounds__(1024, 4)
void caps_pass_f32(const float* __restrict__ x, const float* __restrict__ W,
                   const float* __restrict__ vsumg, float* __restrict__ sdst)
{
    __shared__ float wlds[2][8192];
    const int tid = threadIdx.x, lane = tid & 63;
    const int c = tid & 31, dh = (tid >> 5) & 1, w = tid >> 6;
    const int r0 = blockIdx.x * RB, b0 = w << 2;
    const int key = (c & 7) << 4;
    const int cb  = (c << 10) + (dh << 5);

    float sacc[4][8];
#pragma unroll
    for (int q = 0; q < 4; ++q)
#pragma unroll
        for (int k = 0; k < 8; ++k) sacc[q][k] = 0.0f;

    float vreg[4][8];
    if (!FIRST) {
#pragma unroll
        for (int q = 0; q < 4; ++q) {
            const float4* vp = (const float4*)(vsumg + ((((b0+q) << 5) + c) << 4) + (dh << 3));
            float4 a = vp[0], bq = vp[1];
            vreg[q][0]=a.x; vreg[q][1]=a.y; vreg[q][2]=a.z; vreg[q][3]=a.w;
            vreg[q][4]=bq.x; vreg[q][5]=bq.y; vreg[q][6]=bq.z; vreg[q][7]=bq.w;
        }
    }

    const int Dloc0 = (w << 11);
    const int lx0 = (lane << 4) ^ ((((w << 1))     & 7) << 4);
    const int lx1 = (lane << 4) ^ ((((w << 1) | 1) & 7) << 4);
    const int wu = __builtin_amdgcn_readfirstlane(w);
    const float* xw = x + (size_t)((wu << 2) * R_ + r0) * 16;

#define STAGE(buf, r)                                                              \
    do {                                                                           \
        const char* wr_ = (const char*)W + ((size_t)(r) << 15);                    \
        gload_lds16(wr_ + Dloc0        + lx0, (char*)wlds[buf] + Dloc0);           \
        gload_lds16(wr_ + Dloc0 + 1024 + lx1, (char*)wlds[buf] + Dloc0 + 1024);    \
    } while (0)

    STAGE(0, r0);
#pragma unroll 1
    for (int t = 0; t < RB; ++t) {
        const int cur = t & 1;
        if (t + 1 < RB) { STAGE(cur ^ 1, r0 + t + 1); asm volatile("s_waitcnt vmcnt(2)" ::: "memory"); }
        else            { asm volatile("s_waitcnt vmcnt(0)" ::: "memory"); }
        __builtin_amdgcn_s_barrier();
        __builtin_amdgcn_sched_barrier(0);

        const char* lb = (const char*)wlds[cur];
        float u[4][8];
#pragma unroll
        for (int q = 0; q < 4; ++q)
#pragma unroll
            for (int k = 0; k < 8; ++k) u[q][k] = 0.0f;

#pragma unroll
        for (int i = 0; i < 16; ++i) {
            const int A = (cb + (i << 6)) ^ key;
            float4 w0 = *(const float4*)(lb + A);
            float4 w1 = *(const float4*)(lb + (A ^ 16));
            float wv[8] = {w0.x, w0.y, w0.z, w0.w, w1.x, w1.y, w1.z, w1.w};
#pragma unroll
            for (int q = 0; q < 4; ++q) {
                const float xv = xw[(size_t)q * (R_ * 16) + t * 16 + i];
#pragma unroll
                for (int k = 0; k < 8; ++k) u[q][k] = fmaf(xv, wv[k], u[q][k]);
            }
        }

#pragma unroll
        for (int q = 0; q < 4; ++q) {
            float cij;
            if (FIRST) cij = 0.03125f;
            else {
                float th = 0.0f;
#pragma unroll
                for (int k = 0; k < 8; ++k) th = fmaf(u[q][k], vreg[q][k], th);
                th += __shfl_xor(th, 32);
                float m = th;
#pragma unroll
                for (int off = 16; off >= 1; off >>= 1) m = fmaxf(m, __shfl_xor(m, off));
                const float e = __expf(th - m);
                float ssum = e;
#pragma unroll
                for (int off = 16; off >= 1; off >>= 1) ssum += __shfl_xor(ssum, off);
                cij = e / ssum;
            }
#pragma unroll
            for (int k = 0; k < 8; ++k) sacc[q][k] = fmaf(cij, u[q][k], sacc[q][k]);
        }
        __builtin_amdgcn_s_barrier();
    }
#undef STAGE

#pragma unroll
    for (int q = 0; q < 4; ++q) {
        float* sp = sdst + ((((b0+q) << 5) + c) << 4) + (dh << 3);
#pragma unroll
        for (int k = 0; k < 8; ++k) atomicAdd(sp + k, sacc[q][k]);
    }
}

// ---------------------------------------------------------------- launcher
extern "C" void kernel_launch(void* const* d_in, const int* in_sizes, int n_in,
                              void* d_out, int out_size, void* d_ws, size_t ws_size,
                              hipStream_t stream)
{
    const float* x = (const float*)d_in[0];          // [64, 4608, 16]
    const float* W = (const float*)d_in[1];          // [4608, 32, 16, 16]
    float* out = (float*)d_out;                      // [64, 32, 16]

    const size_t XAB = (size_t)R_ * 64 * 16 * sizeof(_Float16);      //  9,437,184
    const size_t SPB = (size_t)NBLK * SELEM * sizeof(float);         // 16,777,216
    const size_t S2B = (size_t)8 * SELEM * sizeof(float);
    const size_t VSB = (size_t)SELEM * sizeof(float);
    char* wsc = (char*)d_ws;
    const dim3 pgrid(NBLK, 2);

    if (ws_size >= XAB + SPB + S2B + VSB) {
        _Float16* xa  = (_Float16*)wsc;
        float* s_part = (float*)(wsc + XAB);
        float* s2     = (float*)(wsc + XAB + SPB);
        float* vsumT  = (float*)(wsc + XAB + SPB + S2B);

        caps_xconv<<<576, 512, 0, stream>>>(x, xa);

        caps_mfma<true ><<<pgrid, 1024, 0, stream>>>(xa, W, nullptr, s_part);
        caps_reduce1<<<dim3(128, 8), 256, 0, stream>>>(s_part, s2);
        caps_reduce2T<<<32, 64, 0, stream>>>(s2, vsumT, nullptr, 0);

        caps_mfma<false><<<pgrid, 1024, 0, stream>>>(xa, W, vsumT, s_part);
        caps_reduce1<<<dim3(128, 8), 256, 0, stream>>>(s_part, s2);
        caps_reduce2T<<<32, 64, 0, stream>>>(s2, vsumT, nullptr, 1);

        caps_mfma<false><<<pgrid, 1024, 0, stream>>>(xa, W, vsumT, s_part);
        caps_reduce1<<<dim3(128, 8), 256, 0, stream>>>(s_part, s2);
        caps_reduce2T<<<32, 64, 0, stream>>>(s2, vsumT, out, 2);
    } else {
        // tiny-ws fallback: fp32 VALU path (atomic accumulate, old layout)
        float* s    = (float*)wsc;
        float* vsum = s + SELEM;

        hipMemsetAsync(s, 0, VSB, stream);
        caps_pass_f32<true><<<NBLK, 1024, 0, stream>>>(x, W, nullptr, s);
        caps_reduce2<<<128, 256, 0, stream>>>(s, 1, vsum, nullptr, 0);

        hipMemsetAsync(s, 0, VSB, stream);
        caps_pass_f32<false><<<NBLK, 1024, 0, stream>>>(x, W, vsum, s);
        caps_reduce2<<<128, 256, 0, stream>>>(s, 1, vsum, nullptr, 1);

        hipMemsetAsync(s, 0, VSB, stream);
        caps_pass_f32<false><<<NBLK, 1024, 0, stream>>>(x, W, vsum, s);
        caps_reduce2<<<128, 256, 0, stream>>>(s, 1, nullptr, out, 2);
    }
}

// Round 11
// 155.802 us; speedup vs baseline: 1.1665x; 1.1665x over previous
//
#include <hip/hip_runtime.h>
#include <math.h>

// Capsule dynamic routing, B=64, R=4608, C=32, Din=Dout=16, 3 iters.
// b-logits are linear in v -> keep only vsum; u_hat recomputed per pass via
// mfma_f32_32x32x16_f16 (K=16==Din, A=Wfrag, B=xfrag -> D[(c,o)][b]).
//
// Round-11: exact round-7 structure (best measured: 156.7us) with ONE change:
// caps_wprep is now LDS-free. Hypothesis: the ~85us conv pin was 64KB-LDS
// blocks -> 2 blocks/CU -> phase-serialized stage/drain/transpose with too
// little cross-block overlap (invisible in VALU/LDS/FETCH counters). The
// gather version: wave = one wp fragment row; 8 scalar f32 loads/thread at
// 64B stride (lines fully consumed by the 16 o-lanes -> no amplification),
// cvt, one coalesced 1KB/wave half8 store. No LDS, full occupancy, max MLP.

#define B_    64
#define R_    4608
#define C_    32
#define RB    18
#define NBLK  (R_ / RB)      // 256
#define SELEM 32768          // 512 * 64

typedef _Float16 half8  __attribute__((ext_vector_type(8)));
typedef _Float16 half2v __attribute__((ext_vector_type(2)));
typedef float    f32x16 __attribute__((ext_vector_type(16)));

__device__ __forceinline__ void gload_lds16(const void* g, void* l) {
    __builtin_amdgcn_global_load_lds(
        (const __attribute__((address_space(1))) void*)g,
        (__attribute__((address_space(3))) void*)l, 16, 0, 0);
}

// ------------------------------------------------------------------ prep
// x [64][4608][16] f32  ->  xa [4608][64][16] f16
__global__ __launch_bounds__(256)
void caps_prep(const float* __restrict__ x, _Float16* __restrict__ xa)
{
    const int idx = blockIdx.x * 256 + threadIdx.x;   // idx = r*64 + b
    const int r = idx >> 6, b = idx & 63;
    const float4* xs = (const float4*)(x + ((size_t)b * R_ + r) * 16);
    const float4 A = xs[0], Bv = xs[1], Cv = xs[2], Dv = xs[3];
    half8 lo, hi;
    lo[0]=(_Float16)A.x;  lo[1]=(_Float16)A.y;  lo[2]=(_Float16)A.z;  lo[3]=(_Float16)A.w;
    lo[4]=(_Float16)Bv.x; lo[5]=(_Float16)Bv.y; lo[6]=(_Float16)Bv.z; lo[7]=(_Float16)Bv.w;
    hi[0]=(_Float16)Cv.x; hi[1]=(_Float16)Cv.y; hi[2]=(_Float16)Cv.z; hi[3]=(_Float16)Cv.w;
    hi[4]=(_Float16)Dv.x; hi[5]=(_Float16)Dv.y; hi[6]=(_Float16)Dv.z; hi[7]=(_Float16)Dv.w;
    half8* dst = (half8*)(xa + ((size_t)idx << 4));
    dst[0] = lo; dst[1] = hi;
}

// ------------------------------------------------------------------ wprep
// LDS-free gather conversion. Wave-unit u = r*16 + nt produces the 1KB wp
// fragment row wp[u*512 + lane*8 + e] = (f16) W[r][2nt+(l31>>4)][8h+e][l31&15].
// Per instr (fixed e): lanes cover 2c x 2h x 16o = 4 full 64B lines.
// Grid: 2304 blocks x 512 threads; each wave handles 4 consecutive units.
__global__ __launch_bounds__(512)
void caps_wprep(const float* __restrict__ W, _Float16* __restrict__ wp)
{
    const int wu   = (blockIdx.x * 512 + threadIdx.x) >> 6;  // global wave id
    const int lane = threadIdx.x & 63;
    const int h    = lane >> 5;
    const int l31  = lane & 31;
    const int cp   = l31 >> 4;
    const int o    = l31 & 15;

#pragma unroll
    for (int i = 0; i < 4; ++i) {
        const int u  = wu * 4 + i;                 // < 73728 = 4608*16
        const int r  = u >> 4;
        const int nt = u & 15;
        const float* src = W + (((size_t)r * 32 + 2 * nt + cp) * 16 + 8 * h) * 16 + o;
        half8 f;
#pragma unroll
        for (int e = 0; e < 8; ++e)
            f[e] = (_Float16)src[e * 16];
        *(half8*)(wp + (size_t)u * 512 + lane * 8) = f;
    }
}

// ------------------------------------------------------------- MFMA pass
// D = mfma(A=Wfrag, B=xfrag): D[row=(cc,o)][col=b_loc].
// lane: col b_loc = lane&31; rows (regs): R(e,h) = (e&3)+8*(e>>2)+4*h.
// global row g = (2wv+j)*32 + R -> c = g>>4, o = g&15.
template<bool FIRST>
__global__ __launch_bounds__(512, 4)
void caps_mfma(const _Float16* __restrict__ xa, const _Float16* __restrict__ wp,
               const float* __restrict__ vsumT, float* __restrict__ sdst)
{
    __shared__ _Float16 xalds[RB * 512];      // 18 KB
    __shared__ float t_lds[32][33];
    __shared__ float c_lds[32][33];

    const int tid  = threadIdx.x;
    const int lane = tid & 63;
    const int wv   = tid >> 6;                // 0..7
    const int h    = lane >> 5;
    const int l31  = lane & 31;
    const int bh   = blockIdx.y;              // b-half
    const int r0   = blockIdx.x * RB;
    const int bg   = bh * 32 + l31;           // global b owned by this lane

    // stage x tile (coalesced; involution swizzle validated in round 6)
    {
        const int slx = (lane << 4) ^ (((lane >> 3) & 7) << 4);
        for (int t = wv; t < RB; t += 8) {
            const char* src = (const char*)xa + (size_t)(r0 + t) * 2048 + bh * 1024 + slx;
            gload_lds16(src, (char*)xalds + t * 1024);
        }
    }

    f32x16 sacc0, sacc1, zf;
#pragma unroll
    for (int k = 0; k < 16; ++k) { sacc0[k] = 0.f; sacc1[k] = 0.f; zf[k] = 0.f; }

    // v[b][c][o] per lane, f16-packed (16 VGPRs): vh[j][e>>1][e&1] = v at reg e
    half2v vh[2][8];
    if (!FIRST) {
#pragma unroll
        for (int j = 0; j < 2; ++j)
#pragma unroll
            for (int e = 0; e < 16; ++e) {
                const int g = (2 * wv + j) * 32 + (e & 3) + 8 * (e >> 2) + 4 * h;
                vh[j][e >> 1][e & 1] = (_Float16)vsumT[(size_t)g * 64 + bg];
            }
    }

    asm volatile("s_waitcnt vmcnt(0)" ::: "memory");
    __syncthreads();

    const int avoff = ((l31 << 5) + (h << 4)) ^ (((l31 >> 2) & 7) << 4);

    const size_t wstride = 16 * 64 * 8;       // f16 per r
    const _Float16* wpb = wp + (((size_t)r0 * 16 + 2 * wv) * 64 + lane) * 8;
    half8 bc0 = *(const half8*)wpb;
    half8 bc1 = *(const half8*)(wpb + 512);

#pragma unroll 1
    for (int t = 0; t < RB; ++t) {
        const half8 av = *(const half8*)((const char*)xalds + t * 1024 + avoff);

        f32x16 u0, u1;
        if (FIRST) {
            sacc0 = __builtin_amdgcn_mfma_f32_32x32x16_f16(bc0, av, sacc0, 0, 0, 0);
            sacc1 = __builtin_amdgcn_mfma_f32_32x32x16_f16(bc1, av, sacc1, 0, 0, 0);
        } else {
            u0 = __builtin_amdgcn_mfma_f32_32x32x16_f16(bc0, av, zf, 0, 0, 0);
            u1 = __builtin_amdgcn_mfma_f32_32x32x16_f16(bc1, av, zf, 0, 0, 0);
        }

        // prefetch next r's W-frags (clamped tail re-load harmless)
        const int tn = (t < RB - 1) ? (t + 1) : t;
        const _Float16* wpn = wp + ((size_t)(r0 + tn)) * wstride + ((size_t)(2 * wv) * 64 + lane) * 8;
        bc0 = *(const half8*)wpn;
        bc1 = *(const half8*)(wpn + 512);

        if (FIRST) continue;

        // ---- logits: in-register o-reduce + one half-swap fold per capsule
        float tc[2][2];
#pragma unroll
        for (int j = 0; j < 2; ++j) {
            const f32x16& u = j ? u1 : u0;
            float s0 = 0.f, s1 = 0.f;
#pragma unroll
            for (int e2 = 0; e2 < 4; ++e2) {
                s0 += u[2 * e2]     * (float)vh[j][e2][0];
                s0 += u[2 * e2 + 1] * (float)vh[j][e2][1];
                s1 += u[8 + 2 * e2]     * (float)vh[j][4 + e2][0];
                s1 += u[8 + 2 * e2 + 1] * (float)vh[j][4 + e2][1];
            }
            s0 += __shfl_xor(s0, 32);
            s1 += __shfl_xor(s1, 32);
            tc[j][0] = s0; tc[j][1] = s1;
        }
        if (h == 0) {
            t_lds[4 * wv    ][l31] = tc[0][0];
            t_lds[4 * wv + 1][l31] = tc[0][1];
            t_lds[4 * wv + 2][l31] = tc[1][0];
            t_lds[4 * wv + 3][l31] = tc[1][1];
        }
        __syncthreads();

        // ---- softmax over c: thread -> (c-pair a_, local b2) ----
        {
            const int a_ = lane & 15;
            const int b2 = tid >> 4;          // 0..31
            const float tA = t_lds[2 * a_][b2];
            const float tB = t_lds[2 * a_ + 1][b2];
            float m = fmaxf(tA, tB);
            m = fmaxf(m, __shfl_xor(m, 1));
            m = fmaxf(m, __shfl_xor(m, 2));
            m = fmaxf(m, __shfl_xor(m, 4));
            m = fmaxf(m, __shfl_xor(m, 8));
            const float eA = __expf(tA - m);
            const float eB = __expf(tB - m);
            float zs = eA + eB;
            zs += __shfl_xor(zs, 1);
            zs += __shfl_xor(zs, 2);
            zs += __shfl_xor(zs, 4);
            zs += __shfl_xor(zs, 8);
            const float inv = 1.0f / zs;
            c_lds[2 * a_][b2]     = eA * inv;
            c_lds[2 * a_ + 1][b2] = eB * inv;
        }
        __syncthreads();

        // ---- accumulate: sacc += c_ij * u (2 broadcast b32 reads per tile)
#pragma unroll
        for (int j = 0; j < 2; ++j) {
            const f32x16& u = j ? u1 : u0;
            f32x16& sa = j ? sacc1 : sacc0;
            const float c0v = c_lds[4 * wv + 2 * j    ][l31];
            const float c1v = c_lds[4 * wv + 2 * j + 1][l31];
#pragma unroll
            for (int e = 0; e < 8; ++e)  sa[e]     += c0v * u[e];
#pragma unroll
            for (int e = 8; e < 16; ++e) sa[e]     += c1v * u[e];
        }
    }

    // ---- epilogue: transposed partial store sT[g][b] (coalesced over b) ----
    const float scale = FIRST ? 0.03125f : 1.0f;
    float* sp = sdst + ((size_t)blockIdx.x << 15);
#pragma unroll
    for (int j = 0; j < 2; ++j) {
        const f32x16& sa = j ? sacc1 : sacc0;
#pragma unroll
        for (int e = 0; e < 16; ++e) {
            const int g = (2 * wv + j) * 32 + (e & 3) + 8 * (e >> 2) + 4 * h;
            sp[(size_t)g * 64 + bg] = sa[e] * scale;
        }
    }
}

// ------------------------------------------------- reductions + squash
// stage 1: 256 partials -> 8 (elementwise, layout-agnostic)
__global__ __launch_bounds__(256)
void caps_reduce1(const float* __restrict__ sp, float* __restrict__ s2)
{
    const int e  = blockIdx.x * 256 + threadIdx.x;
    const int pg = blockIdx.y;
    const float* p0 = sp + (size_t)pg * 32 * SELEM + e;
    float a = 0.0f;
#pragma unroll 8
    for (int p = 0; p < 32; ++p) a += p0[(size_t)p * SELEM];
    s2[pg * SELEM + e] = a;
}

// stage 2 on transposed layout: thread owns (c,b), o in registers -> no shfl.
// mode 0: vsumT = v; 1: vsumT += v; 2: out[b][c][o] = v.
__global__ __launch_bounds__(64)
void caps_reduce2T(const float* __restrict__ src, float* __restrict__ vsumT,
                   float* __restrict__ out, int mode)
{
    const int c = blockIdx.x;                 // 0..31
    const int b = threadIdx.x;                // 0..63
    float a[16];
#pragma unroll
    for (int o = 0; o < 16; ++o) a[o] = 0.0f;
    for (int p = 0; p < 8; ++p)
#pragma unroll
        for (int o = 0; o < 16; ++o)
            a[o] += src[(size_t)p * SELEM + c * 1024 + o * 64 + b];
    float sq = 0.0f;
#pragma unroll
    for (int o = 0; o < 16; ++o) sq += a[o] * a[o];
    const float n  = sqrtf(sq);
    const float sc = sq / (1.0f + sq) / (n + 1e-8f);
    if (mode == 2) {
#pragma unroll
        for (int o = 0; o < 16; ++o)
            out[(size_t)b * 512 + c * 16 + o] = a[o] * sc;
    } else if (mode == 0) {
#pragma unroll
        for (int o = 0; o < 16; ++o)
            vsumT[c * 1024 + o * 64 + b] = a[o] * sc;
    } else {
#pragma unroll
        for (int o = 0; o < 16; ++o)
            vsumT[c * 1024 + o * 64 + b] += a[o] * sc;
    }
}

// old-layout reduce2 (tier-3 fallback only)
__global__ __launch_bounds__(256)
void caps_reduce2(const float* __restrict__ src, int P,
                  float* __restrict__ vsum, float* __restrict__ out, int mode)
{
    const int e = blockIdx.x * 256 + threadIdx.x;
    float a = 0.0f;
    for (int p = 0; p < P; ++p) a += src[(size_t)p * SELEM + e];
    float sq = a * a;
#pragma unroll
    for (int off = 8; off >= 1; off >>= 1) sq += __shfl_xor(sq, off);
    const float n = sqrtf(sq);
    const float v = a * (sq / (1.0f + sq) / (n + 1e-8f));
    if (mode == 0)      vsum[e] = v;
    else if (mode == 1) vsum[e] += v;
    else                out[e] = v;
}

// ------------------------------------- tier-3 fallback: fp32 VALU path
template<bool FIRST>
__global__ __launch_bounds__(1024, 4)
void caps_pass_f32(const float* __restrict__ x, const float* __restrict__ W,
                   const float* __restrict__ vsumg, float* __restrict__ sdst)
{
    __shared__ float wlds[2][8192];
    const int tid = threadIdx.x, lane = tid & 63;
    const int c = tid & 31, dh = (tid >> 5) & 1, w = tid >> 6;
    const int r0 = blockIdx.x * RB, b0 = w << 2;
    const int key = (c & 7) << 4;
    const int cb  = (c << 10) + (dh << 5);

    float sacc[4][8];
#pragma unroll
    for (int q = 0; q < 4; ++q)
#pragma unroll
        for (int k = 0; k < 8; ++k) sacc[q][k] = 0.0f;

    float vreg[4][8];
    if (!FIRST) {
#pragma unroll
        for (int q = 0; q < 4; ++q) {
            const float4* vp = (const float4*)(vsumg + ((((b0+q) << 5) + c) << 4) + (dh << 3));
            float4 a = vp[0], bq = vp[1];
            vreg[q][0]=a.x; vreg[q][1]=a.y; vreg[q][2]=a.z; vreg[q][3]=a.w;
            vreg[q][4]=bq.x; vreg[q][5]=bq.y; vreg[q][6]=bq.z; vreg[q][7]=bq.w;
        }
    }

    const int Dloc0 = (w << 11);
    const int lx0 = (lane << 4) ^ ((((w << 1))     & 7) << 4);
    const int lx1 = (lane << 4) ^ ((((w << 1) | 1) & 7) << 4);
    const int wu = __builtin_amdgcn_readfirstlane(w);
    const float* xw = x + (size_t)((wu << 2) * R_ + r0) * 16;

#define STAGE(buf, r)                                                              \
    do {                                                                           \
        const char* wr_ = (const char*)W + ((size_t)(r) << 15);                    \
        gload_lds16(wr_ + Dloc0        + lx0, (char*)wlds[buf] + Dloc0);           \
        gload_lds16(wr_ + Dloc0 + 1024 + lx1, (char*)wlds[buf] + Dloc0 + 1024);    \
    } while (0)

    STAGE(0, r0);
#pragma unroll 1
    for (int t = 0; t < RB; ++t) {
        const int cur = t & 1;
        if (t + 1 < RB) { STAGE(cur ^ 1, r0 + t + 1); asm volatile("s_waitcnt vmcnt(2)" ::: "memory"); }
        else            { asm volatile("s_waitcnt vmcnt(0)" ::: "memory"); }
        __builtin_amdgcn_s_barrier();
        __builtin_amdgcn_sched_barrier(0);

        const char* lb = (const char*)wlds[cur];
        float u[4][8];
#pragma unroll
        for (int q = 0; q < 4; ++q)
#pragma unroll
            for (int k = 0; k < 8; ++k) u[q][k] = 0.0f;

#pragma unroll
        for (int i = 0; i < 16; ++i) {
            const int A = (cb + (i << 6)) ^ key;
            float4 w0 = *(const float4*)(lb + A);
            float4 w1 = *(const float4*)(lb + (A ^ 16));
            float wv[8] = {w0.x, w0.y, w0.z, w0.w, w1.x, w1.y, w1.z, w1.w};
#pragma unroll
            for (int q = 0; q < 4; ++q) {
                const float xv = xw[(size_t)q * (R_ * 16) + t * 16 + i];
#pragma unroll
                for (int k = 0; k < 8; ++k) u[q][k] = fmaf(xv, wv[k], u[q][k]);
            }
        }

#pragma unroll
        for (int q = 0; q < 4; ++q) {
            float cij;
            if (FIRST) cij = 0.03125f;
            else {
                float th = 0.0f;
#pragma unroll
                for (int k = 0; k < 8; ++k) th = fmaf(u[q][k], vreg[q][k], th);
                th += __shfl_xor(th, 32);
                float m = th;
#pragma unroll
                for (int off = 16; off >= 1; off >>= 1) m = fmaxf(m, __shfl_xor(m, off));
                const float e = __expf(th - m);
                float ssum = e;
#pragma unroll
                for (int off = 16; off >= 1; off >>= 1) ssum += __shfl_xor(ssum, off);
                cij = e / ssum;
            }
#pragma unroll
            for (int k = 0; k < 8; ++k) sacc[q][k] = fmaf(cij, u[q][k], sacc[q][k]);
        }
        __builtin_amdgcn_s_barrier();
    }
#undef STAGE

#pragma unroll
    for (int q = 0; q < 4; ++q) {
        float* sp = sdst + ((((b0+q) << 5) + c) << 4) + (dh << 3);
#pragma unroll
        for (int k = 0; k < 8; ++k) atomicAdd(sp + k, sacc[q][k]);
    }
}

// ---------------------------------------------------------------- launcher
extern "C" void kernel_launch(void* const* d_in, const int* in_sizes, int n_in,
                              void* d_out, int out_size, void* d_ws, size_t ws_size,
                              hipStream_t stream)
{
    const float* x = (const float*)d_in[0];          // [64, 4608, 16]
    const float* W = (const float*)d_in[1];          // [4608, 32, 16, 16]
    float* out = (float*)d_out;                      // [64, 32, 16]

    const size_t WPB = (size_t)R_ * 16 * 64 * 8 * sizeof(_Float16);  // 75,497,472
    const size_t XAB = (size_t)R_ * 64 * 16 * sizeof(_Float16);      //  9,437,184
    const size_t SPB = (size_t)NBLK * SELEM * sizeof(float);         // 33,554,432
    const size_t S2B = (size_t)8 * SELEM * sizeof(float);
    const size_t VSB = (size_t)SELEM * sizeof(float);
    char* wsc = (char*)d_ws;
    const dim3 pgrid(NBLK, 2);

    if (ws_size >= WPB + XAB + SPB + S2B + VSB) {
        _Float16* wp  = (_Float16*)wsc;
        _Float16* xa  = (_Float16*)(wsc + WPB);
        float* s_part = (float*)(wsc + WPB + XAB);
        float* s2     = (float*)(wsc + WPB + XAB + SPB);
        float* vsumT  = (float*)(wsc + WPB + XAB + SPB + S2B);

        caps_prep<<<1152, 256, 0, stream>>>(x, xa);
        caps_wprep<<<2304, 512, 0, stream>>>(W, wp);

        caps_mfma<true ><<<pgrid, 512, 0, stream>>>(xa, wp, nullptr, s_part);
        caps_reduce1<<<dim3(128, 8), 256, 0, stream>>>(s_part, s2);
        caps_reduce2T<<<32, 64, 0, stream>>>(s2, vsumT, nullptr, 0);

        caps_mfma<false><<<pgrid, 512, 0, stream>>>(xa, wp, vsumT, s_part);
        caps_reduce1<<<dim3(128, 8), 256, 0, stream>>>(s_part, s2);
        caps_reduce2T<<<32, 64, 0, stream>>>(s2, vsumT, nullptr, 1);

        caps_mfma<false><<<pgrid, 512, 0, stream>>>(xa, wp, vsumT, s_part);
        caps_reduce1<<<dim3(128, 8), 256, 0, stream>>>(s_part, s2);
        caps_reduce2T<<<32, 64, 0, stream>>>(s2, vsumT, out, 2);
    } else {
        // tiny-ws fallback: fp32 VALU path (atomic accumulate, old layout)
        float* s    = (float*)wsc;
        float* vsum = s + SELEM;

        hipMemsetAsync(s, 0, VSB, stream);
        caps_pass_f32<true><<<NBLK, 1024, 0, stream>>>(x, W, nullptr, s);
        caps_reduce2<<<128, 256, 0, stream>>>(s, 1, vsum, nullptr, 0);

        hipMemsetAsync(s, 0, VSB, stream);
        caps_pass_f32<false><<<NBLK, 1024, 0, stream>>>(x, W, vsum, s);
        caps_reduce2<<<128, 256, 0, stream>>>(s, 1, vsum, nullptr, 1);

        hipMemsetAsync(s, 0, VSB, stream);
        caps_pass_f32<false><<<NBLK, 1024, 0, stream>>>(x, W, vsum, s);
        caps_reduce2<<<128, 256, 0, stream>>>(s, 1, nullptr, out, 2);
    }
}